// Round 16
// baseline (295.941 us; speedup 1.0000x reference)
//
#include <hip/hip_runtime.h>
#include <hip/hip_bf16.h>
#include <math.h>

#define N_NODES_C 100000
#define N_EDGES_C 1600000
#define N_GRAPHS_C 512
#define BSHIFT 7
#define BSIZE (1 << BSHIFT)
#define NBUCK ((N_NODES_C + BSIZE - 1) >> BSHIFT)   // 782
#define CHUNK_A 2048
#define NCH ((N_EDGES_C + CHUNK_A - 1) / CHUNK_A)   // 782

typedef unsigned int  uint_t;
typedef unsigned short ushort_t;
typedef __attribute__((ext_vector_type(8))) short bf16x8;
typedef __attribute__((ext_vector_type(4))) float f32x4;

__device__ __forceinline__ float elu_f(float x) { return x > 0.f ? x : expm1f(x); }

// bf16 helpers (RNE pack, shift unpack). Finite values only.
__device__ __forceinline__ ushort_t f2bf(float f) {
    uint_t u = __float_as_uint(f);
    u += 0x7FFFu + ((u >> 16) & 1u);
    return (ushort_t)(u >> 16);
}
__device__ __forceinline__ uint_t pack2bf(float lo, float hi) {
    return (uint_t)f2bf(lo) | ((uint_t)f2bf(hi) << 16);
}
__device__ __forceinline__ float bf_lo(uint_t u) { return __uint_as_float(u << 16); }
__device__ __forceinline__ float bf_hi(uint_t u) { return __uint_as_float(u & 0xFFFF0000u); }
__device__ __forceinline__ float bf2f(ushort_t u) { return __uint_as_float(((uint_t)u) << 16); }

__device__ __forceinline__ int wave_incl_scan(int v) {
    int lane = threadIdx.x & 63;
#pragma unroll
    for (int o = 1; o < 64; o <<= 1) {
        int t = __shfl_up(v, o);
        if (lane >= o) v += t;
    }
    return v;
}

// ---------------------------------------------------------------------------
// f32 -> bf16 conversion of input features (8 elems/thread).
// ---------------------------------------------------------------------------
__global__ __launch_bounds__(256) void cvt_bf16(
    const float* __restrict__ in, uint_t* __restrict__ out, int n8)
{
    int i = blockIdx.x * 256 + threadIdx.x;
    if (i >= n8) return;
    const float4* p = reinterpret_cast<const float4*>(in) + 2 * i;
    float4 a = p[0], b = p[1];
    uint4 o;
    o.x = pack2bf(a.x, a.y); o.y = pack2bf(a.z, a.w);
    o.z = pack2bf(b.x, b.y); o.w = pack2bf(b.z, b.w);
    reinterpret_cast<uint4*>(out)[i] = o;
}

// ---------------------------------------------------------------------------
// All three transposed+concatenated bf16 weight tensors in ONE launch.
//   wcat[n][k] = (k < DIN ? w_rel[k][n] : w_root[k-DIN][n]),  [DOUT][2*DIN]
// ---------------------------------------------------------------------------
__device__ __forceinline__ void emit_wcat(
    const float* wr, const float* wt, ushort_t* o, int DIN, int DOUT, int sub)
{
    int idx = sub * 256 + threadIdx.x;
    int KT = 2 * DIN;
    if (idx >= DOUT * KT) return;
    int n = idx / KT, k = idx % KT;
    float v = (k < DIN) ? wr[k * DOUT + n] : wt[(k - DIN) * DOUT + n];
    o[idx] = f2bf(v);
}

__global__ __launch_bounds__(256) void build_wcat_all(
    const float* __restrict__ w1r, const float* __restrict__ w1t,
    const float* __restrict__ w2r, const float* __restrict__ w2t,
    const float* __restrict__ w3r, const float* __restrict__ w3t,
    ushort_t* __restrict__ wc1, ushort_t* __restrict__ wc2,
    ushort_t* __restrict__ wc3)
{
    int bid = blockIdx.x;
    if (bid < 8)       emit_wcat(w1r, w1t, wc1, 32, 32, bid);
    else if (bid < 24) emit_wcat(w2r, w2t, wc2, 32, 64, bid - 8);
    else               emit_wcat(w3r, w3t, wc3, 64, 64, bid - 24);
}

// ---------------------------------------------------------------------------
// Bucketed CSR build v4: chunk-major ccnt/cbase (coalesced in count/pass;
// v3's bucket-major layout made 611K scattered 4B accesses in bucket_pass).
// ebuf packed: (local_dst:7b << 17) | src:17b.
// ---------------------------------------------------------------------------
__global__ __launch_bounds__(256) void bucket_count(
    const int* __restrict__ dst, int* __restrict__ ccnt, int nE)
{
    __shared__ int cnt[NBUCK];
    int t = threadIdx.x;
    for (int i = t; i < NBUCK; i += 256) cnt[i] = 0;
    __syncthreads();
    int lo = blockIdx.x * CHUNK_A;
    int hi = lo + CHUNK_A;
    if (hi > nE) hi = nE;
    for (int e = lo + t; e < hi; e += 256)
        atomicAdd(&cnt[dst[e] >> BSHIFT], 1);
    __syncthreads();
    int* orow = ccnt + (size_t)blockIdx.x * NBUCK;
    for (int i = t; i < NBUCK; i += 256) orow[i] = cnt[i];  // coalesced
}

// thread = bucket; walk chunks; reads/writes coalesced across threads.
__global__ __launch_bounds__(256) void scan_chunks(
    const int* __restrict__ ccnt, int* __restrict__ cbase, int* __restrict__ btot)
{
    int b = blockIdx.x * 256 + threadIdx.x;
    if (b >= NBUCK) return;
    int running = 0;
    for (int c = 0; c < NCH; ++c) {
        int v = ccnt[(size_t)c * NBUCK + b];
        cbase[(size_t)c * NBUCK + b] = running;
        running += v;
    }
    btot[b] = running;
}

__global__ __launch_bounds__(1024) void bucket_scan(
    const int* __restrict__ btot, int* __restrict__ bucket_base, int nE)
{
    int tid = threadIdx.x;  // NBUCK <= 1024
    int v = tid < NBUCK ? btot[tid] : 0;
    int lane = tid & 63, w = tid >> 6;  // 16 waves
    int incl = wave_incl_scan(v);
    __shared__ int ws[16];
    if (lane == 63) ws[w] = incl;
    __syncthreads();
    int woff = 0;
    for (int i = 0; i < w; ++i) woff += ws[i];
    if (tid < NBUCK) bucket_base[tid] = woff + incl - v;
    if (tid == 0) bucket_base[NBUCK] = nE;
}

__global__ __launch_bounds__(256) void bucket_pass(
    const int* __restrict__ src, const int* __restrict__ dst,
    const int* __restrict__ bucket_base, const int* __restrict__ cbase,
    int* __restrict__ ebuf, int nE)
{
    __shared__ int cnt[NBUCK];
    __shared__ int base[NBUCK];
    int t = threadIdx.x;
    int cid = blockIdx.x;
    const int* crow = cbase + (size_t)cid * NBUCK;
    for (int i = t; i < NBUCK; i += 256) {
        cnt[i] = 0;
        base[i] = bucket_base[i] + crow[i];  // coalesced
    }
    __syncthreads();

    int lo = cid * CHUNK_A;
    int hi = lo + CHUNK_A;
    if (hi > nE) hi = nE;
    for (int e = lo + t; e < hi; e += 256) {
        int d = dst[e];
        int b = d >> BSHIFT;
        int p = base[b] + atomicAdd(&cnt[b], 1);
        ebuf[p] = ((d & (BSIZE - 1)) << 17) | src[e];
    }
}

__global__ __launch_bounds__(256) void bucket_build(
    const int* __restrict__ bucket_base, const int* __restrict__ ebuf,
    int* __restrict__ row_start, int* __restrict__ ssrc)
{
    int b = blockIdx.x;
    int nlo = b << BSHIFT;
    int nhi = nlo + BSIZE;
    if (nhi > N_NODES_C) nhi = N_NODES_C;
    int nloc = nhi - nlo;

    __shared__ int degl[BSIZE];
    __shared__ int posl[BSIZE];
    __shared__ int ws[4];
    int t = threadIdx.x;

    if (t < BSIZE) degl[t] = 0;
    __syncthreads();

    int lo = bucket_base[b];
    int hi = bucket_base[b + 1];
    for (int e = lo + t; e < hi; e += 256)
        atomicAdd(&degl[ebuf[e] >> 17], 1);
    __syncthreads();

    int v = (t < nloc) ? degl[t] : 0;
    int incl = wave_incl_scan(v);
    int lane = t & 63, w = t >> 6;
    if (lane == 63) ws[w] = incl;
    __syncthreads();
    int woff = 0;
    for (int i = 0; i < w; ++i) woff += ws[i];
    int pp = lo + woff + incl - v;
    if (t < nloc) { row_start[nlo + t] = pp; posl[t] = pp; }
    if (t == 0 && nhi == N_NODES_C) row_start[N_NODES_C] = hi;
    __syncthreads();

    for (int e = lo + t; e < hi; e += 256) {
        int x = ebuf[e];
        int q = atomicAdd(&posl[x >> 17], 1);
        ssrc[q] = x & 0x1FFFF;
    }
}

// ---------------------------------------------------------------------------
// Fused layer: gather-sum (bf16, f32 acc) into a small LDS tile, barrier,
// then MFMA transform (round-13 verified fragment layouts). No global agg.
//   A-frag agg-half: LDS (pitch DIN/2+2 uints, bank-safe); x-half: global.
// ---------------------------------------------------------------------------
template<int DIN, int DOUT>
__global__ __launch_bounds__(256) void layer_fused(
    const ushort_t* __restrict__ xb, const int* __restrict__ row_start,
    const int* __restrict__ ssrc, const ushort_t* __restrict__ wcatT,
    const float* __restrict__ bias, ushort_t* __restrict__ out, int nNodes)
{
    constexpr int L = DIN / 8;          // gather lanes per node
    constexpr int NPB = 256 / L;        // nodes per block (64 / 64 / 32)
    constexpr int PITCHU = DIN / 2 + 2; // uints per row (even -> 8B align)
    constexpr int KT = 2 * DIN;
    constexpr int NKB = KT / 32;
    constexpr int NTILES = DOUT / 16;
    constexpr int MT = NPB / 16;        // m-tiles per block

    __shared__ uint_t al[NPB * PITCHU];

    int t = threadIdx.x;
    int n0 = blockIdx.x * NPB;

    // ---- phase 1: gather into LDS (packed bf16) ----
    {
        int ln = t / L, lane = t % L;
        int n = n0 + ln;
        float4 accA = make_float4(0.f, 0.f, 0.f, 0.f);
        float4 accB = accA;
        if (n < nNodes) {
            int beg = row_start[n], end = row_start[n + 1];
            int e = beg;
#pragma unroll 1
            for (; e + 1 < end; e += 2) {
                int s0 = ssrc[e], s1 = ssrc[e + 1];
                uint4 u0 = reinterpret_cast<const uint4*>(xb + (size_t)s0 * DIN)[lane];
                uint4 u1 = reinterpret_cast<const uint4*>(xb + (size_t)s1 * DIN)[lane];
                accA.x += bf_lo(u0.x) + bf_lo(u1.x);
                accA.y += bf_hi(u0.x) + bf_hi(u1.x);
                accA.z += bf_lo(u0.y) + bf_lo(u1.y);
                accA.w += bf_hi(u0.y) + bf_hi(u1.y);
                accB.x += bf_lo(u0.z) + bf_lo(u1.z);
                accB.y += bf_hi(u0.z) + bf_hi(u1.z);
                accB.z += bf_lo(u0.w) + bf_lo(u1.w);
                accB.w += bf_hi(u0.w) + bf_hi(u1.w);
            }
            if (e < end) {
                int s0 = ssrc[e];
                uint4 u0 = reinterpret_cast<const uint4*>(xb + (size_t)s0 * DIN)[lane];
                accA.x += bf_lo(u0.x); accA.y += bf_hi(u0.x);
                accA.z += bf_lo(u0.y); accA.w += bf_hi(u0.y);
                accB.x += bf_lo(u0.z); accB.y += bf_hi(u0.z);
                accB.z += bf_lo(u0.w); accB.w += bf_hi(u0.w);
            }
        }
        uint_t* lr = &al[ln * PITCHU + lane * 4];
        lr[0] = pack2bf(accA.x, accA.y);
        lr[1] = pack2bf(accA.z, accA.w);
        lr[2] = pack2bf(accB.x, accB.y);
        lr[3] = pack2bf(accB.z, accB.w);
    }
    __syncthreads();

    // ---- phase 2: MFMA transform ----
    int wid  = t >> 6;
    int lane = t & 63;
    int l15  = lane & 15;
    int lg   = lane >> 4;

    int ntile, mt0, nmt;
    if (NTILES == 4) { ntile = wid;     mt0 = 0;                    nmt = MT; }
    else             { ntile = wid & 1; nmt = MT / 2; mt0 = (wid >> 1) * nmt; }
    int ncol = ntile * 16 + l15;

    bf16x8 bfrag[NKB];
    {
        const ushort_t* wrow = wcatT + (size_t)ncol * KT;
#pragma unroll
        for (int kb = 0; kb < NKB; ++kb) {
            int kbase = kb * 32 + lg * 4;
            union { uint2 u[2]; bf16x8 v; } cvt;
            cvt.u[0] = *reinterpret_cast<const uint2*>(wrow + kbase);
            cvt.u[1] = *reinterpret_cast<const uint2*>(wrow + kbase + 16);
            bfrag[kb] = cvt.v;
        }
    }
    float bj = bias[ncol];

    for (int mi = 0; mi < nmt; ++mi) {
        int mt = mt0 + mi;
        f32x4 acc = {0.f, 0.f, 0.f, 0.f};
#pragma unroll
        for (int kb = 0; kb < NKB; ++kb) {
            union { uint2 u[2]; bf16x8 v; } cvt;
            if (kb < NKB / 2) {
                int base = (mt * 16 + l15) * PITCHU + kb * 16 + lg * 2;
                cvt.u[0] = *reinterpret_cast<const uint2*>(&al[base]);
                cvt.u[1] = *reinterpret_cast<const uint2*>(&al[base + 8]);
            } else {
                int row = n0 + mt * 16 + l15;
                int kloc = kb * 32 - DIN;
                if (row < nNodes) {
                    const ushort_t* ar = xb + (size_t)row * DIN + kloc + lg * 4;
                    cvt.u[0] = *reinterpret_cast<const uint2*>(ar);
                    cvt.u[1] = *reinterpret_cast<const uint2*>(ar + 16);
                } else {
                    cvt.u[0] = make_uint2(0, 0);
                    cvt.u[1] = make_uint2(0, 0);
                }
            }
            acc = __builtin_amdgcn_mfma_f32_16x16x32_bf16(cvt.v, bfrag[kb], acc, 0, 0, 0);
        }
#pragma unroll
        for (int r = 0; r < 4; ++r) {
            int orow = n0 + mt * 16 + lg * 4 + r;
            if (orow < nNodes)
                out[(size_t)orow * DOUT + ncol] = f2bf(elu_f(acc[r] + bj));
        }
    }
}

// ---------------------------------------------------------------------------
// Fused mean-pool + MLP + log_softmax: one 256-thread block per graph.
// Graph boundaries via binary search on sorted batch; exact counts; no
// atomics, no zero-init memset.
// ---------------------------------------------------------------------------
__global__ __launch_bounds__(256) void pool_mlp(
    const ushort_t* __restrict__ h, const int* __restrict__ batch,
    const float* __restrict__ fw1, const float* __restrict__ fb1,
    const float* __restrict__ fw2, const float* __restrict__ fb2,
    const float* __restrict__ fw3, const float* __restrict__ fb3,
    float* __restrict__ out, int nNodes)
{
    int g = blockIdx.x;
    int t = threadIdx.x;
    int j = t & 63;
    int sub = t >> 6;

    // lower_bound(batch, g) and lower_bound(batch, g+1)
    int lo, hi;
    {
        int a = 0, b = nNodes;
        while (a < b) { int m = (a + b) >> 1; if (batch[m] < g) a = m + 1; else b = m; }
        lo = a;
        b = nNodes;
        while (a < b) { int m = (a + b) >> 1; if (batch[m] < g + 1) a = m + 1; else b = m; }
        hi = a;
    }

    __shared__ float ps[4][64];
    __shared__ float p[64];
    __shared__ float z1[64];
    __shared__ float z2[32];
    __shared__ float z3[10];
    __shared__ float lse;

    float acc = 0.f;
    for (int n = lo + sub; n < hi; n += 4)
        acc += bf2f(h[(size_t)n * 64 + j]);
    ps[sub][j] = acc;
    __syncthreads();

    if (t < 64) {
        float c = (float)((hi - lo) > 0 ? (hi - lo) : 1);
        p[t] = (ps[0][t] + ps[1][t] + ps[2][t] + ps[3][t]) / c;
    }
    __syncthreads();

    if (t < 64) {
        float a = fb1[t];
#pragma unroll
        for (int k = 0; k < 64; ++k) a += p[k] * fw1[k * 64 + t];
        z1[t] = elu_f(a);
    }
    __syncthreads();

    if (t < 32) {
        float a2 = fb2[t];
#pragma unroll
        for (int k = 0; k < 64; ++k) a2 += z1[k] * fw2[k * 32 + t];
        z2[t] = elu_f(a2);
    }
    __syncthreads();

    if (t < 10) {
        float a3 = fb3[t];
#pragma unroll
        for (int k = 0; k < 32; ++k) a3 += z2[k] * fw3[k * 10 + t];
        z3[t] = a3;
    }
    __syncthreads();

    if (t == 0) {
        float m = -1e30f;
        for (int i = 0; i < 10; ++i) m = fmaxf(m, z3[i]);
        float s = 0.f;
        for (int i = 0; i < 10; ++i) s += expf(z3[i] - m);
        lse = logf(s) + m;
    }
    __syncthreads();

    if (t < 10) out[(size_t)g * 10 + t] = z3[t] - lse;
}

// ---------------------------------------------------------------------------
extern "C" void kernel_launch(void* const* d_in, const int* in_sizes, int n_in,
                              void* d_out, int out_size, void* d_ws, size_t ws_size,
                              hipStream_t stream)
{
    const float* x       = (const float*)d_in[0];
    const int*   ei      = (const int*)  d_in[1];
    const int*   batch   = (const int*)  d_in[2];
    const float* w1_rel  = (const float*)d_in[3];
    const float* b1      = (const float*)d_in[4];
    const float* w1_root = (const float*)d_in[5];
    const float* w2_rel  = (const float*)d_in[6];
    const float* b2      = (const float*)d_in[7];
    const float* w2_root = (const float*)d_in[8];
    const float* w3_rel  = (const float*)d_in[9];
    const float* b3      = (const float*)d_in[10];
    const float* w3_root = (const float*)d_in[11];
    const float* fw1     = (const float*)d_in[12];
    const float* fb1     = (const float*)d_in[13];
    const float* fw2     = (const float*)d_in[14];
    const float* fb2     = (const float*)d_in[15];
    const float* fw3     = (const float*)d_in[16];
    const float* fb3     = (const float*)d_in[17];
    float* out = (float*)d_out;

    const int* src = ei;
    const int* dst = ei + N_EDGES_C;

    // workspace layout
    ushort_t* xb  = (ushort_t*)d_ws;                         // N*32 bf16 (6.4MB)
    ushort_t* h1  = xb + (size_t)N_NODES_C * 32;             // N*32 bf16
    ushort_t* h2  = h1 + (size_t)N_NODES_C * 32;             // N*64 bf16
    ushort_t* h3  = h2 + (size_t)N_NODES_C * 64;             // N*64 bf16
    int*   row_start = (int*)(h3 + (size_t)N_NODES_C * 64);  // N+1 int
    int*   btot = row_start + N_NODES_C + 1;                 // NBUCK
    int*   bucket_base = btot + NBUCK;                       // NBUCK+1
    int*   ccnt = bucket_base + NBUCK + 1;                   // NCH*NBUCK (chunk-major)
    int*   cbase = ccnt + (size_t)NCH * NBUCK;               // NCH*NBUCK
    int*   ssrc = cbase + (size_t)NCH * NBUCK;               // nE int
    int*   ebuf = ssrc + N_EDGES_C;                          // nE int
    ushort_t* wc1 = (ushort_t*)((((size_t)(ebuf + N_EDGES_C)) + 15) & ~(size_t)15);
    ushort_t* wc2 = wc1 + 2048;                              // [64][64]
    ushort_t* wc3 = wc2 + 4096;                              // [64][128]

    // ---- prep: input f32->bf16, weights transposed+concatenated ----
    cvt_bf16<<<(N_NODES_C * 32 / 8 + 255) / 256, 256, 0, stream>>>(
        x, (uint_t*)xb, N_NODES_C * 32 / 8);
    build_wcat_all<<<56, 256, 0, stream>>>(
        w1_rel, w1_root, w2_rel, w2_root, w3_rel, w3_root, wc1, wc2, wc3);

    // ---- bucketed CSR build v4 (chunk-major scan matrices) ----
    bucket_count<<<NCH, 256, 0, stream>>>(dst, ccnt, N_EDGES_C);
    scan_chunks<<<(NBUCK + 255) / 256, 256, 0, stream>>>(ccnt, cbase, btot);
    bucket_scan<<<1, 1024, 0, stream>>>(btot, bucket_base, N_EDGES_C);
    bucket_pass<<<NCH, 256, 0, stream>>>(src, dst, bucket_base, cbase, ebuf, N_EDGES_C);
    bucket_build<<<NBUCK, 256, 0, stream>>>(bucket_base, ebuf, row_start, ssrc);

    // ---- fused layers: gather(LDS) + MFMA transform ----
    layer_fused<32, 32><<<(N_NODES_C + 63) / 64, 256, 0, stream>>>(
        xb, row_start, ssrc, wc1, b1, h1, N_NODES_C);
    layer_fused<32, 64><<<(N_NODES_C + 63) / 64, 256, 0, stream>>>(
        h1, row_start, ssrc, wc2, b2, h2, N_NODES_C);
    layer_fused<64, 64><<<(N_NODES_C + 31) / 32, 256, 0, stream>>>(
        h2, row_start, ssrc, wc3, b3, h3, N_NODES_C);

    // ---- fused mean-pool + MLP + log_softmax ----
    pool_mlp<<<N_GRAPHS_C, 256, 0, stream>>>(
        h3, batch, fw1, fb1, fw2, fb2, fw3, fb3, out, N_NODES_C);
}

// Round 17
// 199.164 us; speedup vs baseline: 1.4859x; 1.4859x over previous
//
#include <hip/hip_runtime.h>
#include <hip/hip_bf16.h>
#include <math.h>

#define N_NODES_C 100000
#define N_EDGES_C 1600000
#define N_GRAPHS_C 512
#define BSHIFT 7
#define BSIZE (1 << BSHIFT)
#define NBUCK ((N_NODES_C + BSIZE - 1) >> BSHIFT)   // 782
#define CHUNK_A 2048
#define NCH ((N_EDGES_C + CHUNK_A - 1) / CHUNK_A)   // 782
#define SEG 64
#define NSEG ((NCH + SEG - 1) / SEG)                // 13

typedef unsigned int  uint_t;
typedef unsigned short ushort_t;
typedef __attribute__((ext_vector_type(8))) short bf16x8;
typedef __attribute__((ext_vector_type(4))) float f32x4;

__device__ __forceinline__ float elu_f(float x) { return x > 0.f ? x : expm1f(x); }

// bf16 helpers (RNE pack, shift unpack). Finite values only.
__device__ __forceinline__ ushort_t f2bf(float f) {
    uint_t u = __float_as_uint(f);
    u += 0x7FFFu + ((u >> 16) & 1u);
    return (ushort_t)(u >> 16);
}
__device__ __forceinline__ uint_t pack2bf(float lo, float hi) {
    return (uint_t)f2bf(lo) | ((uint_t)f2bf(hi) << 16);
}
__device__ __forceinline__ float bf_lo(uint_t u) { return __uint_as_float(u << 16); }
__device__ __forceinline__ float bf_hi(uint_t u) { return __uint_as_float(u & 0xFFFF0000u); }
__device__ __forceinline__ float bf2f(ushort_t u) { return __uint_as_float(((uint_t)u) << 16); }

__device__ __forceinline__ int wave_incl_scan(int v) {
    int lane = threadIdx.x & 63;
#pragma unroll
    for (int o = 1; o < 64; o <<= 1) {
        int t = __shfl_up(v, o);
        if (lane >= o) v += t;
    }
    return v;
}

// ---------------------------------------------------------------------------
// f32 -> bf16 conversion of input features (8 elems/thread).
// ---------------------------------------------------------------------------
__global__ __launch_bounds__(256) void cvt_bf16(
    const float* __restrict__ in, uint_t* __restrict__ out, int n8)
{
    int i = blockIdx.x * 256 + threadIdx.x;
    if (i >= n8) return;
    const float4* p = reinterpret_cast<const float4*>(in) + 2 * i;
    float4 a = p[0], b = p[1];
    uint4 o;
    o.x = pack2bf(a.x, a.y); o.y = pack2bf(a.z, a.w);
    o.z = pack2bf(b.x, b.y); o.w = pack2bf(b.z, b.w);
    reinterpret_cast<uint4*>(out)[i] = o;
}

// ---------------------------------------------------------------------------
// All three transposed+concatenated bf16 weight tensors in ONE launch.
// ---------------------------------------------------------------------------
__device__ __forceinline__ void emit_wcat(
    const float* wr, const float* wt, ushort_t* o, int DIN, int DOUT, int sub)
{
    int idx = sub * 256 + threadIdx.x;
    int KT = 2 * DIN;
    if (idx >= DOUT * KT) return;
    int n = idx / KT, k = idx % KT;
    float v = (k < DIN) ? wr[k * DOUT + n] : wt[(k - DIN) * DOUT + n];
    o[idx] = f2bf(v);
}

__global__ __launch_bounds__(256) void build_wcat_all(
    const float* __restrict__ w1r, const float* __restrict__ w1t,
    const float* __restrict__ w2r, const float* __restrict__ w2t,
    const float* __restrict__ w3r, const float* __restrict__ w3t,
    ushort_t* __restrict__ wc1, ushort_t* __restrict__ wc2,
    ushort_t* __restrict__ wc3)
{
    int bid = blockIdx.x;
    if (bid < 8)       emit_wcat(w1r, w1t, wc1, 32, 32, bid);
    else if (bid < 24) emit_wcat(w2r, w2t, wc2, 32, 64, bid - 8);
    else               emit_wcat(w3r, w3t, wc3, 64, 64, bid - 24);
}

// ---------------------------------------------------------------------------
// Bucketed CSR build v5: chunk-major ccnt/cbase (coalesced count/pass) +
// HIERARCHICAL scan (v4's thread-per-bucket serial scan over 782 chunks was
// a 107us latency chain at 0.14% occupancy).
// ebuf packed: (local_dst:7b << 17) | src:17b.
// ---------------------------------------------------------------------------
__global__ __launch_bounds__(256) void bucket_count(
    const int* __restrict__ dst, int* __restrict__ ccnt, int nE)
{
    __shared__ int cnt[NBUCK];
    int t = threadIdx.x;
    for (int i = t; i < NBUCK; i += 256) cnt[i] = 0;
    __syncthreads();
    int lo = blockIdx.x * CHUNK_A;
    int hi = lo + CHUNK_A;
    if (hi > nE) hi = nE;
    for (int e = lo + t; e < hi; e += 256)
        atomicAdd(&cnt[dst[e] >> BSHIFT], 1);
    __syncthreads();
    int* orow = ccnt + (size_t)blockIdx.x * NBUCK;
    for (int i = t; i < NBUCK; i += 256) orow[i] = cnt[i];  // coalesced
}

// A: per-segment bucket sums. 64 independent coalesced loads per thread.
__global__ __launch_bounds__(256) void seg_sums(
    const int* __restrict__ ccnt, int* __restrict__ sseg)
{
    int s = blockIdx.y;
    int b = blockIdx.x * 256 + threadIdx.x;
    if (b >= NBUCK) return;
    int c0 = s * SEG;
    int c1 = c0 + SEG; if (c1 > NCH) c1 = NCH;
    int sum = 0;
#pragma unroll 8
    for (int c = c0; c < c1; ++c)
        sum += ccnt[(size_t)c * NBUCK + b];
    sseg[(size_t)s * NBUCK + b] = sum;
}

// B: exclusive scan over 13 segments, thread per bucket; also bucket totals.
__global__ __launch_bounds__(256) void scan_seg(
    int* __restrict__ sseg, int* __restrict__ btot)
{
    int b = blockIdx.x * 256 + threadIdx.x;
    if (b >= NBUCK) return;
    int run = 0;
#pragma unroll
    for (int s = 0; s < NSEG; ++s) {
        int v = sseg[(size_t)s * NBUCK + b];
        sseg[(size_t)s * NBUCK + b] = run;
        run += v;
    }
    btot[b] = run;
}

// C: within-segment running scan, batch-8 loads to break the latency chain.
__global__ __launch_bounds__(256) void scan_fine(
    const int* __restrict__ ccnt, const int* __restrict__ sseg,
    int* __restrict__ cbase)
{
    int s = blockIdx.y;
    int b = blockIdx.x * 256 + threadIdx.x;
    if (b >= NBUCK) return;
    int run = sseg[(size_t)s * NBUCK + b];
    int c0 = s * SEG;
    int c1 = c0 + SEG; if (c1 > NCH) c1 = NCH;
    int c = c0;
    for (; c + 8 <= c1; c += 8) {
        int v0 = ccnt[(size_t)(c + 0) * NBUCK + b];
        int v1 = ccnt[(size_t)(c + 1) * NBUCK + b];
        int v2 = ccnt[(size_t)(c + 2) * NBUCK + b];
        int v3 = ccnt[(size_t)(c + 3) * NBUCK + b];
        int v4 = ccnt[(size_t)(c + 4) * NBUCK + b];
        int v5 = ccnt[(size_t)(c + 5) * NBUCK + b];
        int v6 = ccnt[(size_t)(c + 6) * NBUCK + b];
        int v7 = ccnt[(size_t)(c + 7) * NBUCK + b];
        cbase[(size_t)(c + 0) * NBUCK + b] = run; run += v0;
        cbase[(size_t)(c + 1) * NBUCK + b] = run; run += v1;
        cbase[(size_t)(c + 2) * NBUCK + b] = run; run += v2;
        cbase[(size_t)(c + 3) * NBUCK + b] = run; run += v3;
        cbase[(size_t)(c + 4) * NBUCK + b] = run; run += v4;
        cbase[(size_t)(c + 5) * NBUCK + b] = run; run += v5;
        cbase[(size_t)(c + 6) * NBUCK + b] = run; run += v6;
        cbase[(size_t)(c + 7) * NBUCK + b] = run; run += v7;
    }
    for (; c < c1; ++c) {
        int v = ccnt[(size_t)c * NBUCK + b];
        cbase[(size_t)c * NBUCK + b] = run;
        run += v;
    }
}

__global__ __launch_bounds__(1024) void bucket_scan(
    const int* __restrict__ btot, int* __restrict__ bucket_base, int nE)
{
    int tid = threadIdx.x;  // NBUCK <= 1024
    int v = tid < NBUCK ? btot[tid] : 0;
    int lane = tid & 63, w = tid >> 6;  // 16 waves
    int incl = wave_incl_scan(v);
    __shared__ int ws[16];
    if (lane == 63) ws[w] = incl;
    __syncthreads();
    int woff = 0;
    for (int i = 0; i < w; ++i) woff += ws[i];
    if (tid < NBUCK) bucket_base[tid] = woff + incl - v;
    if (tid == 0) bucket_base[NBUCK] = nE;
}

__global__ __launch_bounds__(256) void bucket_pass(
    const int* __restrict__ src, const int* __restrict__ dst,
    const int* __restrict__ bucket_base, const int* __restrict__ cbase,
    int* __restrict__ ebuf, int nE)
{
    __shared__ int cnt[NBUCK];
    __shared__ int base[NBUCK];
    int t = threadIdx.x;
    int cid = blockIdx.x;
    const int* crow = cbase + (size_t)cid * NBUCK;
    for (int i = t; i < NBUCK; i += 256) {
        cnt[i] = 0;
        base[i] = bucket_base[i] + crow[i];  // coalesced
    }
    __syncthreads();

    int lo = cid * CHUNK_A;
    int hi = lo + CHUNK_A;
    if (hi > nE) hi = nE;
    for (int e = lo + t; e < hi; e += 256) {
        int d = dst[e];
        int b = d >> BSHIFT;
        int p = base[b] + atomicAdd(&cnt[b], 1);
        ebuf[p] = ((d & (BSIZE - 1)) << 17) | src[e];
    }
}

__global__ __launch_bounds__(256) void bucket_build(
    const int* __restrict__ bucket_base, const int* __restrict__ ebuf,
    int* __restrict__ row_start, int* __restrict__ ssrc)
{
    int b = blockIdx.x;
    int nlo = b << BSHIFT;
    int nhi = nlo + BSIZE;
    if (nhi > N_NODES_C) nhi = N_NODES_C;
    int nloc = nhi - nlo;

    __shared__ int degl[BSIZE];
    __shared__ int posl[BSIZE];
    __shared__ int ws[4];
    int t = threadIdx.x;

    if (t < BSIZE) degl[t] = 0;
    __syncthreads();

    int lo = bucket_base[b];
    int hi = bucket_base[b + 1];
    for (int e = lo + t; e < hi; e += 256)
        atomicAdd(&degl[ebuf[e] >> 17], 1);
    __syncthreads();

    int v = (t < nloc) ? degl[t] : 0;
    int incl = wave_incl_scan(v);
    int lane = t & 63, w = t >> 6;
    if (lane == 63) ws[w] = incl;
    __syncthreads();
    int woff = 0;
    for (int i = 0; i < w; ++i) woff += ws[i];
    int pp = lo + woff + incl - v;
    if (t < nloc) { row_start[nlo + t] = pp; posl[t] = pp; }
    if (t == 0 && nhi == N_NODES_C) row_start[N_NODES_C] = hi;
    __syncthreads();

    for (int e = lo + t; e < hi; e += 256) {
        int x = ebuf[e];
        int q = atomicAdd(&posl[x >> 17], 1);
        ssrc[q] = x & 0x1FFFF;
    }
}

// ---------------------------------------------------------------------------
// Fused layer: gather-sum (bf16, f32 acc) into a small LDS tile, barrier,
// then MFMA transform (round-13 verified fragment layouts). No global agg.
// ---------------------------------------------------------------------------
template<int DIN, int DOUT>
__global__ __launch_bounds__(256) void layer_fused(
    const ushort_t* __restrict__ xb, const int* __restrict__ row_start,
    const int* __restrict__ ssrc, const ushort_t* __restrict__ wcatT,
    const float* __restrict__ bias, ushort_t* __restrict__ out, int nNodes)
{
    constexpr int L = DIN / 8;          // gather lanes per node
    constexpr int NPB = 256 / L;        // nodes per block (64 / 64 / 32)
    constexpr int PITCHU = DIN / 2 + 2; // uints per row (even -> 8B align)
    constexpr int KT = 2 * DIN;
    constexpr int NKB = KT / 32;
    constexpr int NTILES = DOUT / 16;
    constexpr int MT = NPB / 16;        // m-tiles per block

    __shared__ uint_t al[NPB * PITCHU];

    int t = threadIdx.x;
    int n0 = blockIdx.x * NPB;

    // ---- phase 1: gather into LDS (packed bf16) ----
    {
        int ln = t / L, lane = t % L;
        int n = n0 + ln;
        float4 accA = make_float4(0.f, 0.f, 0.f, 0.f);
        float4 accB = accA;
        if (n < nNodes) {
            int beg = row_start[n], end = row_start[n + 1];
            int e = beg;
#pragma unroll 1
            for (; e + 1 < end; e += 2) {
                int s0 = ssrc[e], s1 = ssrc[e + 1];
                uint4 u0 = reinterpret_cast<const uint4*>(xb + (size_t)s0 * DIN)[lane];
                uint4 u1 = reinterpret_cast<const uint4*>(xb + (size_t)s1 * DIN)[lane];
                accA.x += bf_lo(u0.x) + bf_lo(u1.x);
                accA.y += bf_hi(u0.x) + bf_hi(u1.x);
                accA.z += bf_lo(u0.y) + bf_lo(u1.y);
                accA.w += bf_hi(u0.y) + bf_hi(u1.y);
                accB.x += bf_lo(u0.z) + bf_lo(u1.z);
                accB.y += bf_hi(u0.z) + bf_hi(u1.z);
                accB.z += bf_lo(u0.w) + bf_lo(u1.w);
                accB.w += bf_hi(u0.w) + bf_hi(u1.w);
            }
            if (e < end) {
                int s0 = ssrc[e];
                uint4 u0 = reinterpret_cast<const uint4*>(xb + (size_t)s0 * DIN)[lane];
                accA.x += bf_lo(u0.x); accA.y += bf_hi(u0.x);
                accA.z += bf_lo(u0.y); accA.w += bf_hi(u0.y);
                accB.x += bf_lo(u0.z); accB.y += bf_hi(u0.z);
                accB.z += bf_lo(u0.w); accB.w += bf_hi(u0.w);
            }
        }
        uint_t* lr = &al[ln * PITCHU + lane * 4];
        lr[0] = pack2bf(accA.x, accA.y);
        lr[1] = pack2bf(accA.z, accA.w);
        lr[2] = pack2bf(accB.x, accB.y);
        lr[3] = pack2bf(accB.z, accB.w);
    }
    __syncthreads();

    // ---- phase 2: MFMA transform ----
    int wid  = t >> 6;
    int lane = t & 63;
    int l15  = lane & 15;
    int lg   = lane >> 4;

    int ntile, mt0, nmt;
    if (NTILES == 4) { ntile = wid;     mt0 = 0;                    nmt = MT; }
    else             { ntile = wid & 1; nmt = MT / 2; mt0 = (wid >> 1) * nmt; }
    int ncol = ntile * 16 + l15;

    bf16x8 bfrag[NKB];
    {
        const ushort_t* wrow = wcatT + (size_t)ncol * KT;
#pragma unroll
        for (int kb = 0; kb < NKB; ++kb) {
            int kbase = kb * 32 + lg * 4;
            union { uint2 u[2]; bf16x8 v; } cvt;
            cvt.u[0] = *reinterpret_cast<const uint2*>(wrow + kbase);
            cvt.u[1] = *reinterpret_cast<const uint2*>(wrow + kbase + 16);
            bfrag[kb] = cvt.v;
        }
    }
    float bj = bias[ncol];

    for (int mi = 0; mi < nmt; ++mi) {
        int mt = mt0 + mi;
        f32x4 acc = {0.f, 0.f, 0.f, 0.f};
#pragma unroll
        for (int kb = 0; kb < NKB; ++kb) {
            union { uint2 u[2]; bf16x8 v; } cvt;
            if (kb < NKB / 2) {
                int base = (mt * 16 + l15) * PITCHU + kb * 16 + lg * 2;
                cvt.u[0] = *reinterpret_cast<const uint2*>(&al[base]);
                cvt.u[1] = *reinterpret_cast<const uint2*>(&al[base + 8]);
            } else {
                int row = n0 + mt * 16 + l15;
                int kloc = kb * 32 - DIN;
                if (row < nNodes) {
                    const ushort_t* ar = xb + (size_t)row * DIN + kloc + lg * 4;
                    cvt.u[0] = *reinterpret_cast<const uint2*>(ar);
                    cvt.u[1] = *reinterpret_cast<const uint2*>(ar + 16);
                } else {
                    cvt.u[0] = make_uint2(0, 0);
                    cvt.u[1] = make_uint2(0, 0);
                }
            }
            acc = __builtin_amdgcn_mfma_f32_16x16x32_bf16(cvt.v, bfrag[kb], acc, 0, 0, 0);
        }
#pragma unroll
        for (int r = 0; r < 4; ++r) {
            int orow = n0 + mt * 16 + lg * 4 + r;
            if (orow < nNodes)
                out[(size_t)orow * DOUT + ncol] = f2bf(elu_f(acc[r] + bj));
        }
    }
}

// ---------------------------------------------------------------------------
// Fused mean-pool + MLP + log_softmax: one 256-thread block per graph.
// ---------------------------------------------------------------------------
__global__ __launch_bounds__(256) void pool_mlp(
    const ushort_t* __restrict__ h, const int* __restrict__ batch,
    const float* __restrict__ fw1, const float* __restrict__ fb1,
    const float* __restrict__ fw2, const float* __restrict__ fb2,
    const float* __restrict__ fw3, const float* __restrict__ fb3,
    float* __restrict__ out, int nNodes)
{
    int g = blockIdx.x;
    int t = threadIdx.x;
    int j = t & 63;
    int sub = t >> 6;

    int lo, hi;
    {
        int a = 0, b = nNodes;
        while (a < b) { int m = (a + b) >> 1; if (batch[m] < g) a = m + 1; else b = m; }
        lo = a;
        b = nNodes;
        while (a < b) { int m = (a + b) >> 1; if (batch[m] < g + 1) a = m + 1; else b = m; }
        hi = a;
    }

    __shared__ float ps[4][64];
    __shared__ float p[64];
    __shared__ float z1[64];
    __shared__ float z2[32];
    __shared__ float z3[10];
    __shared__ float lse;

    float acc = 0.f;
    for (int n = lo + sub; n < hi; n += 4)
        acc += bf2f(h[(size_t)n * 64 + j]);
    ps[sub][j] = acc;
    __syncthreads();

    if (t < 64) {
        float c = (float)((hi - lo) > 0 ? (hi - lo) : 1);
        p[t] = (ps[0][t] + ps[1][t] + ps[2][t] + ps[3][t]) / c;
    }
    __syncthreads();

    if (t < 64) {
        float a = fb1[t];
#pragma unroll
        for (int k = 0; k < 64; ++k) a += p[k] * fw1[k * 64 + t];
        z1[t] = elu_f(a);
    }
    __syncthreads();

    if (t < 32) {
        float a2 = fb2[t];
#pragma unroll
        for (int k = 0; k < 64; ++k) a2 += z1[k] * fw2[k * 32 + t];
        z2[t] = elu_f(a2);
    }
    __syncthreads();

    if (t < 10) {
        float a3 = fb3[t];
#pragma unroll
        for (int k = 0; k < 32; ++k) a3 += z2[k] * fw3[k * 10 + t];
        z3[t] = a3;
    }
    __syncthreads();

    if (t == 0) {
        float m = -1e30f;
        for (int i = 0; i < 10; ++i) m = fmaxf(m, z3[i]);
        float s = 0.f;
        for (int i = 0; i < 10; ++i) s += expf(z3[i] - m);
        lse = logf(s) + m;
    }
    __syncthreads();

    if (t < 10) out[(size_t)g * 10 + t] = z3[t] - lse;
}

// ---------------------------------------------------------------------------
extern "C" void kernel_launch(void* const* d_in, const int* in_sizes, int n_in,
                              void* d_out, int out_size, void* d_ws, size_t ws_size,
                              hipStream_t stream)
{
    const float* x       = (const float*)d_in[0];
    const int*   ei      = (const int*)  d_in[1];
    const int*   batch   = (const int*)  d_in[2];
    const float* w1_rel  = (const float*)d_in[3];
    const float* b1      = (const float*)d_in[4];
    const float* w1_root = (const float*)d_in[5];
    const float* w2_rel  = (const float*)d_in[6];
    const float* b2      = (const float*)d_in[7];
    const float* w2_root = (const float*)d_in[8];
    const float* w3_rel  = (const float*)d_in[9];
    const float* b3      = (const float*)d_in[10];
    const float* w3_root = (const float*)d_in[11];
    const float* fw1     = (const float*)d_in[12];
    const float* fb1     = (const float*)d_in[13];
    const float* fw2     = (const float*)d_in[14];
    const float* fb2     = (const float*)d_in[15];
    const float* fw3     = (const float*)d_in[16];
    const float* fb3     = (const float*)d_in[17];
    float* out = (float*)d_out;

    const int* src = ei;
    const int* dst = ei + N_EDGES_C;

    // workspace layout
    ushort_t* xb  = (ushort_t*)d_ws;                         // N*32 bf16 (6.4MB)
    ushort_t* h1  = xb + (size_t)N_NODES_C * 32;             // N*32 bf16
    ushort_t* h2  = h1 + (size_t)N_NODES_C * 32;             // N*64 bf16
    ushort_t* h3  = h2 + (size_t)N_NODES_C * 64;             // N*64 bf16
    int*   row_start = (int*)(h3 + (size_t)N_NODES_C * 64);  // N+1 int
    int*   btot = row_start + N_NODES_C + 1;                 // NBUCK
    int*   bucket_base = btot + NBUCK;                       // NBUCK+1
    int*   sseg = bucket_base + NBUCK + 1;                   // NSEG*NBUCK
    int*   ccnt = sseg + (size_t)NSEG * NBUCK;               // NCH*NBUCK (chunk-major)
    int*   cbase = ccnt + (size_t)NCH * NBUCK;               // NCH*NBUCK
    int*   ssrc = cbase + (size_t)NCH * NBUCK;               // nE int
    int*   ebuf = ssrc + N_EDGES_C;                          // nE int
    ushort_t* wc1 = (ushort_t*)((((size_t)(ebuf + N_EDGES_C)) + 15) & ~(size_t)15);
    ushort_t* wc2 = wc1 + 2048;                              // [64][64]
    ushort_t* wc3 = wc2 + 4096;                              // [64][128]

    // ---- prep: input f32->bf16, weights transposed+concatenated ----
    cvt_bf16<<<(N_NODES_C * 32 / 8 + 255) / 256, 256, 0, stream>>>(
        x, (uint_t*)xb, N_NODES_C * 32 / 8);
    build_wcat_all<<<56, 256, 0, stream>>>(
        w1_rel, w1_root, w2_rel, w2_root, w3_rel, w3_root, wc1, wc2, wc3);

    // ---- bucketed CSR build v5 (hierarchical scan) ----
    bucket_count<<<NCH, 256, 0, stream>>>(dst, ccnt, N_EDGES_C);
    {
        dim3 g2((NBUCK + 255) / 256, NSEG);
        seg_sums<<<g2, 256, 0, stream>>>(ccnt, sseg);
        scan_seg<<<(NBUCK + 255) / 256, 256, 0, stream>>>(sseg, btot);
        bucket_scan<<<1, 1024, 0, stream>>>(btot, bucket_base, N_EDGES_C);
        scan_fine<<<g2, 256, 0, stream>>>(ccnt, sseg, cbase);
    }
    bucket_pass<<<NCH, 256, 0, stream>>>(src, dst, bucket_base, cbase, ebuf, N_EDGES_C);
    bucket_build<<<NBUCK, 256, 0, stream>>>(bucket_base, ebuf, row_start, ssrc);

    // ---- fused layers: gather(LDS) + MFMA transform ----
    layer_fused<32, 32><<<(N_NODES_C + 63) / 64, 256, 0, stream>>>(
        xb, row_start, ssrc, wc1, b1, h1, N_NODES_C);
    layer_fused<32, 64><<<(N_NODES_C + 63) / 64, 256, 0, stream>>>(
        h1, row_start, ssrc, wc2, b2, h2, N_NODES_C);
    layer_fused<64, 64><<<(N_NODES_C + 31) / 32, 256, 0, stream>>>(
        h2, row_start, ssrc, wc3, b3, h3, N_NODES_C);

    // ---- fused mean-pool + MLP + log_softmax ----
    pool_mlp<<<N_GRAPHS_C, 256, 0, stream>>>(
        h3, batch, fw1, fb1, fw2, fb2, fw3, fb3, out, N_NODES_C);
}

// Round 18
// 192.458 us; speedup vs baseline: 1.5377x; 1.0348x over previous
//
#include <hip/hip_runtime.h>
#include <hip/hip_bf16.h>
#include <math.h>

#define N_NODES_C 100000
#define N_EDGES_C 1600000
#define N_GRAPHS_C 512
#define BSHIFT 7
#define BSIZE (1 << BSHIFT)
#define NBUCK ((N_NODES_C + BSIZE - 1) >> BSHIFT)   // 782
#define CHUNK_A 2048
#define NCH ((N_EDGES_C + CHUNK_A - 1) / CHUNK_A)   // 782
#define SEG 64
#define NSEG ((NCH + SEG - 1) / SEG)                // 13

typedef unsigned int  uint_t;
typedef unsigned short ushort_t;
typedef __attribute__((ext_vector_type(8))) short bf16x8;
typedef __attribute__((ext_vector_type(4))) float f32x4;

__device__ __forceinline__ float elu_f(float x) { return x > 0.f ? x : expm1f(x); }

// bf16 helpers (RNE pack, shift unpack). Finite values only.
__device__ __forceinline__ ushort_t f2bf(float f) {
    uint_t u = __float_as_uint(f);
    u += 0x7FFFu + ((u >> 16) & 1u);
    return (ushort_t)(u >> 16);
}
__device__ __forceinline__ uint_t pack2bf(float lo, float hi) {
    return (uint_t)f2bf(lo) | ((uint_t)f2bf(hi) << 16);
}
__device__ __forceinline__ float bf_lo(uint_t u) { return __uint_as_float(u << 16); }
__device__ __forceinline__ float bf_hi(uint_t u) { return __uint_as_float(u & 0xFFFF0000u); }
__device__ __forceinline__ float bf2f(ushort_t u) { return __uint_as_float(((uint_t)u) << 16); }

__device__ __forceinline__ void acc_u4(float4& a, float4& b, uint4 u) {
    a.x += bf_lo(u.x); a.y += bf_hi(u.x);
    a.z += bf_lo(u.y); a.w += bf_hi(u.y);
    b.x += bf_lo(u.z); b.y += bf_hi(u.z);
    b.z += bf_lo(u.w); b.w += bf_hi(u.w);
}

__device__ __forceinline__ int wave_incl_scan(int v) {
    int lane = threadIdx.x & 63;
#pragma unroll
    for (int o = 1; o < 64; o <<= 1) {
        int t = __shfl_up(v, o);
        if (lane >= o) v += t;
    }
    return v;
}

// ---------------------------------------------------------------------------
// f32 -> bf16 conversion of input features (8 elems/thread).
// ---------------------------------------------------------------------------
__global__ __launch_bounds__(256) void cvt_bf16(
    const float* __restrict__ in, uint_t* __restrict__ out, int n8)
{
    int i = blockIdx.x * 256 + threadIdx.x;
    if (i >= n8) return;
    const float4* p = reinterpret_cast<const float4*>(in) + 2 * i;
    float4 a = p[0], b = p[1];
    uint4 o;
    o.x = pack2bf(a.x, a.y); o.y = pack2bf(a.z, a.w);
    o.z = pack2bf(b.x, b.y); o.w = pack2bf(b.z, b.w);
    reinterpret_cast<uint4*>(out)[i] = o;
}

// ---------------------------------------------------------------------------
// All three transposed+concatenated bf16 weight tensors in ONE launch.
// ---------------------------------------------------------------------------
__device__ __forceinline__ void emit_wcat(
    const float* wr, const float* wt, ushort_t* o, int DIN, int DOUT, int sub)
{
    int idx = sub * 256 + threadIdx.x;
    int KT = 2 * DIN;
    if (idx >= DOUT * KT) return;
    int n = idx / KT, k = idx % KT;
    float v = (k < DIN) ? wr[k * DOUT + n] : wt[(k - DIN) * DOUT + n];
    o[idx] = f2bf(v);
}

__global__ __launch_bounds__(256) void build_wcat_all(
    const float* __restrict__ w1r, const float* __restrict__ w1t,
    const float* __restrict__ w2r, const float* __restrict__ w2t,
    const float* __restrict__ w3r, const float* __restrict__ w3t,
    ushort_t* __restrict__ wc1, ushort_t* __restrict__ wc2,
    ushort_t* __restrict__ wc3)
{
    int bid = blockIdx.x;
    if (bid < 8)       emit_wcat(w1r, w1t, wc1, 32, 32, bid);
    else if (bid < 24) emit_wcat(w2r, w2t, wc2, 32, 64, bid - 8);
    else               emit_wcat(w3r, w3t, wc3, 64, 64, bid - 24);
}

// ---------------------------------------------------------------------------
// Bucketed CSR build v5 (measured-good round 17): chunk-major count/pass +
// hierarchical scan. ebuf packed: (local_dst:7b << 17) | src:17b.
// ---------------------------------------------------------------------------
__global__ __launch_bounds__(256) void bucket_count(
    const int* __restrict__ dst, int* __restrict__ ccnt, int nE)
{
    __shared__ int cnt[NBUCK];
    int t = threadIdx.x;
    for (int i = t; i < NBUCK; i += 256) cnt[i] = 0;
    __syncthreads();
    int lo = blockIdx.x * CHUNK_A;
    int hi = lo + CHUNK_A;
    if (hi > nE) hi = nE;
    for (int e = lo + t; e < hi; e += 256)
        atomicAdd(&cnt[dst[e] >> BSHIFT], 1);
    __syncthreads();
    int* orow = ccnt + (size_t)blockIdx.x * NBUCK;
    for (int i = t; i < NBUCK; i += 256) orow[i] = cnt[i];  // coalesced
}

__global__ __launch_bounds__(256) void seg_sums(
    const int* __restrict__ ccnt, int* __restrict__ sseg)
{
    int s = blockIdx.y;
    int b = blockIdx.x * 256 + threadIdx.x;
    if (b >= NBUCK) return;
    int c0 = s * SEG;
    int c1 = c0 + SEG; if (c1 > NCH) c1 = NCH;
    int sum = 0;
#pragma unroll 8
    for (int c = c0; c < c1; ++c)
        sum += ccnt[(size_t)c * NBUCK + b];
    sseg[(size_t)s * NBUCK + b] = sum;
}

__global__ __launch_bounds__(256) void scan_seg(
    int* __restrict__ sseg, int* __restrict__ btot)
{
    int b = blockIdx.x * 256 + threadIdx.x;
    if (b >= NBUCK) return;
    int run = 0;
#pragma unroll
    for (int s = 0; s < NSEG; ++s) {
        int v = sseg[(size_t)s * NBUCK + b];
        sseg[(size_t)s * NBUCK + b] = run;
        run += v;
    }
    btot[b] = run;
}

__global__ __launch_bounds__(256) void scan_fine(
    const int* __restrict__ ccnt, const int* __restrict__ sseg,
    int* __restrict__ cbase)
{
    int s = blockIdx.y;
    int b = blockIdx.x * 256 + threadIdx.x;
    if (b >= NBUCK) return;
    int run = sseg[(size_t)s * NBUCK + b];
    int c0 = s * SEG;
    int c1 = c0 + SEG; if (c1 > NCH) c1 = NCH;
    int c = c0;
    for (; c + 8 <= c1; c += 8) {
        int v0 = ccnt[(size_t)(c + 0) * NBUCK + b];
        int v1 = ccnt[(size_t)(c + 1) * NBUCK + b];
        int v2 = ccnt[(size_t)(c + 2) * NBUCK + b];
        int v3 = ccnt[(size_t)(c + 3) * NBUCK + b];
        int v4 = ccnt[(size_t)(c + 4) * NBUCK + b];
        int v5 = ccnt[(size_t)(c + 5) * NBUCK + b];
        int v6 = ccnt[(size_t)(c + 6) * NBUCK + b];
        int v7 = ccnt[(size_t)(c + 7) * NBUCK + b];
        cbase[(size_t)(c + 0) * NBUCK + b] = run; run += v0;
        cbase[(size_t)(c + 1) * NBUCK + b] = run; run += v1;
        cbase[(size_t)(c + 2) * NBUCK + b] = run; run += v2;
        cbase[(size_t)(c + 3) * NBUCK + b] = run; run += v3;
        cbase[(size_t)(c + 4) * NBUCK + b] = run; run += v4;
        cbase[(size_t)(c + 5) * NBUCK + b] = run; run += v5;
        cbase[(size_t)(c + 6) * NBUCK + b] = run; run += v6;
        cbase[(size_t)(c + 7) * NBUCK + b] = run; run += v7;
    }
    for (; c < c1; ++c) {
        int v = ccnt[(size_t)c * NBUCK + b];
        cbase[(size_t)c * NBUCK + b] = run;
        run += v;
    }
}

__global__ __launch_bounds__(1024) void bucket_scan(
    const int* __restrict__ btot, int* __restrict__ bucket_base, int nE)
{
    int tid = threadIdx.x;  // NBUCK <= 1024
    int v = tid < NBUCK ? btot[tid] : 0;
    int lane = tid & 63, w = tid >> 6;  // 16 waves
    int incl = wave_incl_scan(v);
    __shared__ int ws[16];
    if (lane == 63) ws[w] = incl;
    __syncthreads();
    int woff = 0;
    for (int i = 0; i < w; ++i) woff += ws[i];
    if (tid < NBUCK) bucket_base[tid] = woff + incl - v;
    if (tid == 0) bucket_base[NBUCK] = nE;
}

__global__ __launch_bounds__(256) void bucket_pass(
    const int* __restrict__ src, const int* __restrict__ dst,
    const int* __restrict__ bucket_base, const int* __restrict__ cbase,
    int* __restrict__ ebuf, int nE)
{
    __shared__ int cnt[NBUCK];
    __shared__ int base[NBUCK];
    int t = threadIdx.x;
    int cid = blockIdx.x;
    const int* crow = cbase + (size_t)cid * NBUCK;
    for (int i = t; i < NBUCK; i += 256) {
        cnt[i] = 0;
        base[i] = bucket_base[i] + crow[i];  // coalesced
    }
    __syncthreads();

    int lo = cid * CHUNK_A;
    int hi = lo + CHUNK_A;
    if (hi > nE) hi = nE;
    for (int e = lo + t; e < hi; e += 256) {
        int d = dst[e];
        int b = d >> BSHIFT;
        int p = base[b] + atomicAdd(&cnt[b], 1);
        ebuf[p] = ((d & (BSIZE - 1)) << 17) | src[e];
    }
}

__global__ __launch_bounds__(256) void bucket_build(
    const int* __restrict__ bucket_base, const int* __restrict__ ebuf,
    int* __restrict__ row_start, int* __restrict__ ssrc)
{
    int b = blockIdx.x;
    int nlo = b << BSHIFT;
    int nhi = nlo + BSIZE;
    if (nhi > N_NODES_C) nhi = N_NODES_C;
    int nloc = nhi - nlo;

    __shared__ int degl[BSIZE];
    __shared__ int posl[BSIZE];
    __shared__ int ws[4];
    int t = threadIdx.x;

    if (t < BSIZE) degl[t] = 0;
    __syncthreads();

    int lo = bucket_base[b];
    int hi = bucket_base[b + 1];
    for (int e = lo + t; e < hi; e += 256)
        atomicAdd(&degl[ebuf[e] >> 17], 1);
    __syncthreads();

    int v = (t < nloc) ? degl[t] : 0;
    int incl = wave_incl_scan(v);
    int lane = t & 63, w = t >> 6;
    if (lane == 63) ws[w] = incl;
    __syncthreads();
    int woff = 0;
    for (int i = 0; i < w; ++i) woff += ws[i];
    int pp = lo + woff + incl - v;
    if (t < nloc) { row_start[nlo + t] = pp; posl[t] = pp; }
    if (t == 0 && nhi == N_NODES_C) row_start[N_NODES_C] = hi;
    __syncthreads();

    for (int e = lo + t; e < hi; e += 256) {
        int x = ebuf[e];
        int q = atomicAdd(&posl[x >> 17], 1);
        ssrc[q] = x & 0x1FFFF;
    }
}

// ---------------------------------------------------------------------------
// Fused layer: gather-sum into LDS + MFMA transform. Gather edge loop is
// 4-deep (round-17 profile: bf16 gather latency-bound at 1.5 TB/s fetch,
// half the f32 path's 3 TB/s — 32 random lines in flight/wave wasn't enough).
// ---------------------------------------------------------------------------
template<int DIN, int DOUT>
__global__ __launch_bounds__(256) void layer_fused(
    const ushort_t* __restrict__ xb, const int* __restrict__ row_start,
    const int* __restrict__ ssrc, const ushort_t* __restrict__ wcatT,
    const float* __restrict__ bias, ushort_t* __restrict__ out, int nNodes)
{
    constexpr int L = DIN / 8;          // gather lanes per node
    constexpr int NPB = 256 / L;        // nodes per block (64 / 64 / 32)
    constexpr int PITCHU = DIN / 2 + 2; // uints per row (even -> 8B align)
    constexpr int KT = 2 * DIN;
    constexpr int NKB = KT / 32;
    constexpr int NTILES = DOUT / 16;
    constexpr int MT = NPB / 16;        // m-tiles per block

    __shared__ uint_t al[NPB * PITCHU];

    int t = threadIdx.x;
    int n0 = blockIdx.x * NPB;

    // ---- phase 1: gather into LDS (packed bf16), 4 edges in flight ----
    {
        int ln = t / L, lane = t % L;
        int n = n0 + ln;
        float4 accA = make_float4(0.f, 0.f, 0.f, 0.f);
        float4 accB = accA;
        if (n < nNodes) {
            int beg = row_start[n], end = row_start[n + 1];
            int e = beg;
#pragma unroll 1
            for (; e + 3 < end; e += 4) {
                int s0 = ssrc[e], s1 = ssrc[e + 1], s2 = ssrc[e + 2], s3 = ssrc[e + 3];
                uint4 u0 = reinterpret_cast<const uint4*>(xb + (size_t)s0 * DIN)[lane];
                uint4 u1 = reinterpret_cast<const uint4*>(xb + (size_t)s1 * DIN)[lane];
                uint4 u2 = reinterpret_cast<const uint4*>(xb + (size_t)s2 * DIN)[lane];
                uint4 u3 = reinterpret_cast<const uint4*>(xb + (size_t)s3 * DIN)[lane];
                acc_u4(accA, accB, u0);
                acc_u4(accA, accB, u1);
                acc_u4(accA, accB, u2);
                acc_u4(accA, accB, u3);
            }
            if (e + 1 < end) {
                int s0 = ssrc[e], s1 = ssrc[e + 1];
                uint4 u0 = reinterpret_cast<const uint4*>(xb + (size_t)s0 * DIN)[lane];
                uint4 u1 = reinterpret_cast<const uint4*>(xb + (size_t)s1 * DIN)[lane];
                acc_u4(accA, accB, u0);
                acc_u4(accA, accB, u1);
                e += 2;
            }
            if (e < end) {
                int s0 = ssrc[e];
                uint4 u0 = reinterpret_cast<const uint4*>(xb + (size_t)s0 * DIN)[lane];
                acc_u4(accA, accB, u0);
            }
        }
        uint_t* lr = &al[ln * PITCHU + lane * 4];
        lr[0] = pack2bf(accA.x, accA.y);
        lr[1] = pack2bf(accA.z, accA.w);
        lr[2] = pack2bf(accB.x, accB.y);
        lr[3] = pack2bf(accB.z, accB.w);
    }
    __syncthreads();

    // ---- phase 2: MFMA transform (round-13 verified fragment layouts) ----
    int wid  = t >> 6;
    int lane = t & 63;
    int l15  = lane & 15;
    int lg   = lane >> 4;

    int ntile, mt0, nmt;
    if (NTILES == 4) { ntile = wid;     mt0 = 0;                    nmt = MT; }
    else             { ntile = wid & 1; nmt = MT / 2; mt0 = (wid >> 1) * nmt; }
    int ncol = ntile * 16 + l15;

    bf16x8 bfrag[NKB];
    {
        const ushort_t* wrow = wcatT + (size_t)ncol * KT;
#pragma unroll
        for (int kb = 0; kb < NKB; ++kb) {
            int kbase = kb * 32 + lg * 4;
            union { uint2 u[2]; bf16x8 v; } cvt;
            cvt.u[0] = *reinterpret_cast<const uint2*>(wrow + kbase);
            cvt.u[1] = *reinterpret_cast<const uint2*>(wrow + kbase + 16);
            bfrag[kb] = cvt.v;
        }
    }
    float bj = bias[ncol];

    for (int mi = 0; mi < nmt; ++mi) {
        int mt = mt0 + mi;
        f32x4 acc = {0.f, 0.f, 0.f, 0.f};
#pragma unroll
        for (int kb = 0; kb < NKB; ++kb) {
            union { uint2 u[2]; bf16x8 v; } cvt;
            if (kb < NKB / 2) {
                int base = (mt * 16 + l15) * PITCHU + kb * 16 + lg * 2;
                cvt.u[0] = *reinterpret_cast<const uint2*>(&al[base]);
                cvt.u[1] = *reinterpret_cast<const uint2*>(&al[base + 8]);
            } else {
                int row = n0 + mt * 16 + l15;
                int kloc = kb * 32 - DIN;
                if (row < nNodes) {
                    const ushort_t* ar = xb + (size_t)row * DIN + kloc + lg * 4;
                    cvt.u[0] = *reinterpret_cast<const uint2*>(ar);
                    cvt.u[1] = *reinterpret_cast<const uint2*>(ar + 16);
                } else {
                    cvt.u[0] = make_uint2(0, 0);
                    cvt.u[1] = make_uint2(0, 0);
                }
            }
            acc = __builtin_amdgcn_mfma_f32_16x16x32_bf16(cvt.v, bfrag[kb], acc, 0, 0, 0);
        }
#pragma unroll
        for (int r = 0; r < 4; ++r) {
            int orow = n0 + mt * 16 + lg * 4 + r;
            if (orow < nNodes)
                out[(size_t)orow * DOUT + ncol] = f2bf(elu_f(acc[r] + bj));
        }
    }
}

// ---------------------------------------------------------------------------
// Fused mean-pool + MLP + log_softmax: one 256-thread block per graph.
// ---------------------------------------------------------------------------
__global__ __launch_bounds__(256) void pool_mlp(
    const ushort_t* __restrict__ h, const int* __restrict__ batch,
    const float* __restrict__ fw1, const float* __restrict__ fb1,
    const float* __restrict__ fw2, const float* __restrict__ fb2,
    const float* __restrict__ fw3, const float* __restrict__ fb3,
    float* __restrict__ out, int nNodes)
{
    int g = blockIdx.x;
    int t = threadIdx.x;
    int j = t & 63;
    int sub = t >> 6;

    int lo, hi;
    {
        int a = 0, b = nNodes;
        while (a < b) { int m = (a + b) >> 1; if (batch[m] < g) a = m + 1; else b = m; }
        lo = a;
        b = nNodes;
        while (a < b) { int m = (a + b) >> 1; if (batch[m] < g + 1) a = m + 1; else b = m; }
        hi = a;
    }

    __shared__ float ps[4][64];
    __shared__ float p[64];
    __shared__ float z1[64];
    __shared__ float z2[32];
    __shared__ float z3[10];
    __shared__ float lse;

    float acc = 0.f;
    for (int n = lo + sub; n < hi; n += 4)
        acc += bf2f(h[(size_t)n * 64 + j]);
    ps[sub][j] = acc;
    __syncthreads();

    if (t < 64) {
        float c = (float)((hi - lo) > 0 ? (hi - lo) : 1);
        p[t] = (ps[0][t] + ps[1][t] + ps[2][t] + ps[3][t]) / c;
    }
    __syncthreads();

    if (t < 64) {
        float a = fb1[t];
#pragma unroll
        for (int k = 0; k < 64; ++k) a += p[k] * fw1[k * 64 + t];
        z1[t] = elu_f(a);
    }
    __syncthreads();

    if (t < 32) {
        float a2 = fb2[t];
#pragma unroll
        for (int k = 0; k < 64; ++k) a2 += z1[k] * fw2[k * 32 + t];
        z2[t] = elu_f(a2);
    }
    __syncthreads();

    if (t < 10) {
        float a3 = fb3[t];
#pragma unroll
        for (int k = 0; k < 32; ++k) a3 += z2[k] * fw3[k * 10 + t];
        z3[t] = a3;
    }
    __syncthreads();

    if (t == 0) {
        float m = -1e30f;
        for (int i = 0; i < 10; ++i) m = fmaxf(m, z3[i]);
        float s = 0.f;
        for (int i = 0; i < 10; ++i) s += expf(z3[i] - m);
        lse = logf(s) + m;
    }
    __syncthreads();

    if (t < 10) out[(size_t)g * 10 + t] = z3[t] - lse;
}

// ---------------------------------------------------------------------------
extern "C" void kernel_launch(void* const* d_in, const int* in_sizes, int n_in,
                              void* d_out, int out_size, void* d_ws, size_t ws_size,
                              hipStream_t stream)
{
    const float* x       = (const float*)d_in[0];
    const int*   ei      = (const int*)  d_in[1];
    const int*   batch   = (const int*)  d_in[2];
    const float* w1_rel  = (const float*)d_in[3];
    const float* b1      = (const float*)d_in[4];
    const float* w1_root = (const float*)d_in[5];
    const float* w2_rel  = (const float*)d_in[6];
    const float* b2      = (const float*)d_in[7];
    const float* w2_root = (const float*)d_in[8];
    const float* w3_rel  = (const float*)d_in[9];
    const float* b3      = (const float*)d_in[10];
    const float* w3_root = (const float*)d_in[11];
    const float* fw1     = (const float*)d_in[12];
    const float* fb1     = (const float*)d_in[13];
    const float* fw2     = (const float*)d_in[14];
    const float* fb2     = (const float*)d_in[15];
    const float* fw3     = (const float*)d_in[16];
    const float* fb3     = (const float*)d_in[17];
    float* out = (float*)d_out;

    const int* src = ei;
    const int* dst = ei + N_EDGES_C;

    // workspace layout
    ushort_t* xb  = (ushort_t*)d_ws;                         // N*32 bf16 (6.4MB)
    ushort_t* h1  = xb + (size_t)N_NODES_C * 32;             // N*32 bf16
    ushort_t* h2  = h1 + (size_t)N_NODES_C * 32;             // N*64 bf16
    ushort_t* h3  = h2 + (size_t)N_NODES_C * 64;             // N*64 bf16
    int*   row_start = (int*)(h3 + (size_t)N_NODES_C * 64);  // N+1 int
    int*   btot = row_start + N_NODES_C + 1;                 // NBUCK
    int*   bucket_base = btot + NBUCK;                       // NBUCK+1
    int*   sseg = bucket_base + NBUCK + 1;                   // NSEG*NBUCK
    int*   ccnt = sseg + (size_t)NSEG * NBUCK;               // NCH*NBUCK (chunk-major)
    int*   cbase = ccnt + (size_t)NCH * NBUCK;               // NCH*NBUCK
    int*   ssrc = cbase + (size_t)NCH * NBUCK;               // nE int
    int*   ebuf = ssrc + N_EDGES_C;                          // nE int
    ushort_t* wc1 = (ushort_t*)((((size_t)(ebuf + N_EDGES_C)) + 15) & ~(size_t)15);
    ushort_t* wc2 = wc1 + 2048;                              // [64][64]
    ushort_t* wc3 = wc2 + 4096;                              // [64][128]

    // ---- prep: input f32->bf16, weights transposed+concatenated ----
    cvt_bf16<<<(N_NODES_C * 32 / 8 + 255) / 256, 256, 0, stream>>>(
        x, (uint_t*)xb, N_NODES_C * 32 / 8);
    build_wcat_all<<<56, 256, 0, stream>>>(
        w1_rel, w1_root, w2_rel, w2_root, w3_rel, w3_root, wc1, wc2, wc3);

    // ---- bucketed CSR build v5 (hierarchical scan) ----
    bucket_count<<<NCH, 256, 0, stream>>>(dst, ccnt, N_EDGES_C);
    {
        dim3 g2((NBUCK + 255) / 256, NSEG);
        seg_sums<<<g2, 256, 0, stream>>>(ccnt, sseg);
        scan_seg<<<(NBUCK + 255) / 256, 256, 0, stream>>>(sseg, btot);
        bucket_scan<<<1, 1024, 0, stream>>>(btot, bucket_base, N_EDGES_C);
        scan_fine<<<g2, 256, 0, stream>>>(ccnt, sseg, cbase);
    }
    bucket_pass<<<NCH, 256, 0, stream>>>(src, dst, bucket_base, cbase, ebuf, N_EDGES_C);
    bucket_build<<<NBUCK, 256, 0, stream>>>(bucket_base, ebuf, row_start, ssrc);

    // ---- fused layers: gather(LDS, 4-deep) + MFMA transform ----
    layer_fused<32, 32><<<(N_NODES_C + 63) / 64, 256, 0, stream>>>(
        xb, row_start, ssrc, wc1, b1, h1, N_NODES_C);
    layer_fused<32, 64><<<(N_NODES_C + 63) / 64, 256, 0, stream>>>(
        h1, row_start, ssrc, wc2, b2, h2, N_NODES_C);
    layer_fused<64, 64><<<(N_NODES_C + 31) / 32, 256, 0, stream>>>(
        h2, row_start, ssrc, wc3, b3, h3, N_NODES_C);

    // ---- fused mean-pool + MLP + log_softmax ----
    pool_mlp<<<N_GRAPHS_C, 256, 0, stream>>>(
        h3, batch, fw1, fb1, fw2, fb2, fw3, fb3, out, N_NODES_C);
}